// Round 9
// baseline (484.921 us; speedup 1.0000x reference)
//
#include <hip/hip_runtime.h>
#include <math.h>

#define BB 2
#define LL 2048
#define DMODEL 1024
#define NHEAD 16
#define MTOK 4096            // BB*LL
#define KVB 64               // attention KV tile rows
#define NT (LL / KVB)        // 32 KV tiles

typedef unsigned short u16;
typedef __attribute__((ext_vector_type(8))) short short8;
typedef __attribute__((ext_vector_type(4))) float f32x4;

// ---------------------------------------------------------------------------
// bf16 split helpers: x ≈ bf2f(hi) + bf2f(lo), residual ~2^-17 x
// ---------------------------------------------------------------------------
__device__ __host__ inline u16 f2bf(float f) {
    unsigned u = __builtin_bit_cast(unsigned, f);
    return (u16)((u + 0x7FFFu + ((u >> 16) & 1u)) >> 16);   // RNE
}
__device__ inline float bf2f(u16 h) {
    unsigned u = ((unsigned)h) << 16;
    return __builtin_bit_cast(float, u);
}

// ---------------------------------------------------------------------------
// fp32 -> (hi,lo) bf16 plane converters, float4-vectorized, multi-tensor.
// ---------------------------------------------------------------------------
__device__ inline void split_one(const float* __restrict__ x, u16* __restrict__ hi,
                                 u16* __restrict__ lo, int n4)
{
    for (int i = blockIdx.x * blockDim.x + threadIdx.x; i < n4;
         i += gridDim.x * blockDim.x) {
        float4 v = ((const float4*)x)[i];
        ushort4 h, l;
        h.x = f2bf(v.x); l.x = f2bf(v.x - bf2f(h.x));
        h.y = f2bf(v.y); l.y = f2bf(v.y - bf2f(h.y));
        h.z = f2bf(v.z); l.z = f2bf(v.z - bf2f(h.z));
        h.w = f2bf(v.w); l.w = f2bf(v.w - bf2f(h.w));
        ((ushort4*)hi)[i] = h;
        ((ushort4*)lo)[i] = l;
    }
}

__global__ __launch_bounds__(256)
void split_planes2(const float* __restrict__ x0, u16* __restrict__ h0, u16* __restrict__ l0,
                   const float* __restrict__ x1, u16* __restrict__ h1, u16* __restrict__ l1,
                   int n4)
{
    if (blockIdx.y == 0) split_one(x0, h0, l0, n4);
    else                 split_one(x1, h1, l1, n4);
}

__global__ __launch_bounds__(256)
void split_planes4(const float* __restrict__ x0, u16* __restrict__ h0, u16* __restrict__ l0,
                   const float* __restrict__ x1, u16* __restrict__ h1, u16* __restrict__ l1,
                   const float* __restrict__ x2, u16* __restrict__ h2, u16* __restrict__ l2,
                   const float* __restrict__ x3, u16* __restrict__ h3, u16* __restrict__ l3,
                   int n4)
{
    switch (blockIdx.y & 3) {
        case 0: split_one(x0, h0, l0, n4); break;
        case 1: split_one(x1, h1, l1, n4); break;
        case 2: split_one(x2, h2, l2, n4); break;
        default: split_one(x3, h3, l3, n4); break;
    }
}

// ---------------------------------------------------------------------------
// Split-bf16 MFMA GEMM v2 (torch Linear NT): BM=BN=128, BK=32, 4 waves,
// wave tile 64x64 (4x4 frags of 16x16x32), dbuf LDS 64 KB.
// Two parameter sets selected by blockIdx.x (>= NX0 -> set 1) so Q and K
// projections fuse into one launch. Staging/swizzle identical family to the
// HW-validated round-3 kernel: src chunk kl = ci ^ ((r>>1)&3), linear LDS.
// mode 0: fp32 Yf [m][Nout]. mode 1: (hi,lo) planes [m][Nout].
// mode 2: transposed planes [n][MTOK], packed 8B stores.
// ---------------------------------------------------------------------------
#define GBK 32

__global__ __launch_bounds__(256, 2)
void gemm_mfma2(const u16* __restrict__ A0hi, const u16* __restrict__ A0lo,
                const u16* __restrict__ B0hi, const u16* __restrict__ B0lo,
                const float* __restrict__ bias0, float scale0,
                u16* __restrict__ Y0hi, u16* __restrict__ Y0lo,
                const u16* __restrict__ A1hi, const u16* __restrict__ A1lo,
                const u16* __restrict__ B1hi, const u16* __restrict__ B1lo,
                const float* __restrict__ bias1, float scale1,
                u16* __restrict__ Y1hi, u16* __restrict__ Y1lo,
                float* __restrict__ Yf, int K, int Nout, int NX0, int mode)
{
    // per buffer (u16): Ahi[0,4096) Alo[4096,8192) Bhi[8192,12288) Blo[12288,16384)
    __shared__ u16 lds[2][16384];

    const int tid = threadIdx.x;
    const int lid = tid & 63;
    const int w   = tid >> 6;
    const int wm  = w >> 1, wn = w & 1;
    const int bx  = blockIdx.x;
    const int set = (bx >= NX0) ? 1 : 0;
    const int n0  = (set ? bx - NX0 : bx) * 128;
    const int m0  = blockIdx.y * 128;

    const u16* Ahi = set ? A1hi : A0hi;
    const u16* Alo = set ? A1lo : A0lo;
    const u16* Bhi = set ? B1hi : B0hi;
    const u16* Blo = set ? B1lo : B0lo;
    const float* bias = set ? bias1 : bias0;
    const float scale = set ? scale1 : scale0;
    u16* Yhi = set ? Y1hi : Y0hi;
    u16* Ylo = set ? Y1lo : Y0lo;

    f32x4 acc[4][4];
    #pragma unroll
    for (int ms = 0; ms < 4; ++ms)
        #pragma unroll
        for (int ns = 0; ns < 4; ++ns)
            acc[ms][ns] = (f32x4){0.f, 0.f, 0.f, 0.f};

    // ---- stage one K-step (32 chunks of 512 u16; 8 per wave) ----
    auto stage = [&](int buf, int t) {
        const int k0 = t * GBK;
        #pragma unroll
        for (int j = 0; j < 8; ++j) {
            const int q = w * 8 + j;
            const u16* plane; int ldsoff, c, R0;
            if (q < 8)       { plane = Ahi; ldsoff = 0;     c = q;      R0 = m0; }
            else if (q < 16) { plane = Alo; ldsoff = 4096;  c = q - 8;  R0 = m0; }
            else if (q < 24) { plane = Bhi; ldsoff = 8192;  c = q - 16; R0 = n0; }
            else             { plane = Blo; ldsoff = 12288; c = q - 24; R0 = n0; }
            const int r  = c * 16 + (lid >> 2);
            const int ci = lid & 3;
            const int kl = ci ^ ((r >> 1) & 3);
            const u16* g = plane + (size_t)(R0 + r) * K + k0 + kl * 8;
            __builtin_amdgcn_global_load_lds(
                (const __attribute__((address_space(1))) void*)g,
                (__attribute__((address_space(3))) void*)(&lds[buf][ldsoff + c * 512]),
                16, 0, 0);
        }
    };

    auto compute = [&](int buf) {
        const u16* L = lds[buf];
        short8 ah[4], al[4], bh[4], bl[4];
        #pragma unroll
        for (int ms = 0; ms < 4; ++ms) {
            const int r   = wm * 64 + ms * 16 + (lid & 15);
            const int off = r * 32 + (((lid >> 4) ^ ((r >> 1) & 3)) * 8);
            ah[ms] = *(const short8*)&L[off];
            al[ms] = *(const short8*)&L[4096 + off];
        }
        #pragma unroll
        for (int ns = 0; ns < 4; ++ns) {
            const int r   = wn * 64 + ns * 16 + (lid & 15);
            const int off = r * 32 + (((lid >> 4) ^ ((r >> 1) & 3)) * 8);
            bh[ns] = *(const short8*)&L[8192 + off];
            bl[ns] = *(const short8*)&L[12288 + off];
        }
        #pragma unroll
        for (int ms = 0; ms < 4; ++ms)
            #pragma unroll
            for (int ns = 0; ns < 4; ++ns) {
                acc[ms][ns] = __builtin_amdgcn_mfma_f32_16x16x32_bf16(al[ms], bh[ns], acc[ms][ns], 0, 0, 0);
                acc[ms][ns] = __builtin_amdgcn_mfma_f32_16x16x32_bf16(ah[ms], bl[ns], acc[ms][ns], 0, 0, 0);
                acc[ms][ns] = __builtin_amdgcn_mfma_f32_16x16x32_bf16(ah[ms], bh[ns], acc[ms][ns], 0, 0, 0);
            }
    };

    const int nt = K / GBK;
    stage(0, 0);
    __syncthreads();
    for (int t = 0; t < nt; ++t) {
        const int buf = t & 1;
        if (t + 1 < nt) stage(buf ^ 1, t + 1);
        compute(buf);
        __syncthreads();
    }

    // ---- epilogue: D layout col = lid&15, row = (lid>>4)*4 + i ----
    const int orow = (lid >> 4) * 4;
    #pragma unroll
    for (int ms = 0; ms < 4; ++ms)
        #pragma unroll
        for (int ns = 0; ns < 4; ++ns) {
            const int col = n0 + wn * 64 + ns * 16 + (lid & 15);
            const float bcol = bias[col];
            if (mode == 2) {
                // packed Vt store: 4 consecutive MTOK elements per lane
                const int r0 = m0 + wm * 64 + ms * 16 + orow;
                unsigned ph[2] = {0, 0}, pl[2] = {0, 0};
                #pragma unroll
                for (int i = 0; i < 4; ++i) {
                    const float y = (acc[ms][ns][i] + bcol) * scale;
                    const u16 hh = f2bf(y);
                    const u16 ll = f2bf(y - bf2f(hh));
                    ph[i >> 1] |= ((unsigned)hh) << ((i & 1) * 16);
                    pl[i >> 1] |= ((unsigned)ll) << ((i & 1) * 16);
                }
                const size_t idx = (size_t)col * MTOK + r0;
                *(uint2*)(Yhi + idx) = make_uint2(ph[0], ph[1]);
                *(uint2*)(Ylo + idx) = make_uint2(pl[0], pl[1]);
            } else {
                #pragma unroll
                for (int i = 0; i < 4; ++i) {
                    const int row = m0 + wm * 64 + ms * 16 + orow + i;
                    const float y = (acc[ms][ns][i] + bcol) * scale;
                    if (mode == 0) {
                        Yf[(size_t)row * Nout + col] = y;
                    } else {
                        const size_t idx = (size_t)row * Nout + col;
                        const u16 hh = f2bf(y);
                        Yhi[idx] = hh;
                        Ylo[idx] = f2bf(y - bf2f(hh));
                    }
                }
            }
        }
}

// ---------------------------------------------------------------------------
// Split-bf16 MFMA flash attention v4: swapped operands, lane-local softmax,
// KVB=64 (per-tile overhead amortized 2x, barriers halved vs v3).
// Block = (b, h, 64 q rows), 4 waves x 16 q rows. KV tiles 64 rows dbuf.
// LDS: pp 16 KB (per-wave fp32 P [16q][64k], 16 f32x4 slots/row, ^q16 swz)
//    + kvb 64 KB ([buf][Kh,Kl,Vth,Vtl][64x64], slot^(r&7) swz) = 80 KB.
// ---------------------------------------------------------------------------
__global__ __launch_bounds__(256, 2)
void attn_mfma4(const u16* __restrict__ qph, const u16* __restrict__ qpl,
                const u16* __restrict__ kph, const u16* __restrict__ kpl,
                const u16* __restrict__ vth, const u16* __restrict__ vtl,
                const float* __restrict__ qmask, const float* __restrict__ kmask,
                const float* __restrict__ pos,
                u16* __restrict__ ach, u16* __restrict__ acl)
{
    __shared__ float pp[4][1024];
    __shared__ u16  kvb[2][4][4096];

    const int tid = threadIdx.x;
    const int lid = tid & 63;
    const int w   = tid >> 6;
    const int q16 = lid & 15;
    const int hi4 = lid >> 4;
    const int qt = blockIdx.x, h = blockIdx.y, b = blockIdx.z;
    const int qw = qt * 64 + w * 16;       // wave's first q row

    // ---- Q B-frags direct from global: q = qw + q16, d = ks*32 + hi4*8 + jj
    short8 qh[2], ql[2];
    #pragma unroll
    for (int ks = 0; ks < 2; ++ks) {
        const size_t off = (size_t)(b * LL + qw + q16) * DMODEL
                         + h * 64 + ks * 32 + hi4 * 8;
        qh[ks] = *(const short8*)(qph + off);
        ql[ks] = *(const short8*)(qpl + off);
    }

    // ---- staging: wave w stages plane w; 8 chunks of 8 rows x 64 u16 ----
    auto stage = [&](int buf, int t) {
        const int k0 = t * KVB;
        u16* dst = &kvb[buf][w][0];
        #pragma unroll
        for (int c = 0; c < 8; ++c) {
            const int r  = c * 8 + (lid >> 3);
            const int sp = (lid & 7) ^ (r & 7);
            const u16* src;
            if (w == 0)      src = kph + (size_t)(b * LL + k0 + r) * DMODEL + h * 64 + sp * 8;
            else if (w == 1) src = kpl + (size_t)(b * LL + k0 + r) * DMODEL + h * 64 + sp * 8;
            else if (w == 2) src = vth + (size_t)(h * 64 + r) * MTOK + b * LL + k0 + sp * 8;
            else             src = vtl + (size_t)(h * 64 + r) * MTOK + b * LL + k0 + sp * 8;
            __builtin_amdgcn_global_load_lds(
                (const __attribute__((address_space(1))) void*)src,
                (__attribute__((address_space(3))) void*)(dst + c * 512), 16, 0, 0);
        }
    };

    float m_run = -INFINITY, l_run = 0.f;
    const float qml = qmask[b * LL + qw + q16];
    const float* prow = pos + (size_t)(b * LL + qw + q16) * LL;
    const float* kmrow = kmask + b * LL;

    f32x4 o_acc[4];
    #pragma unroll
    for (int nfd = 0; nfd < 4; ++nfd)
        o_acc[nfd] = (f32x4){0.f, 0.f, 0.f, 0.f};

    stage(0, 0);
    __syncthreads();

    for (int t = 0; t < NT; ++t) {
        const int buf = t & 1;
        const int k0  = t * KVB;

        // ---- vector pos + kmask loads (in flight under QK^T) ----
        float4 kmv[4], posr[4];
        #pragma unroll
        for (int nf = 0; nf < 4; ++nf) {
            kmv[nf]  = *(const float4*)(kmrow + k0 + nf * 16 + hi4 * 4);
            posr[nf] = *(const float4*)(prow + k0 + nf * 16 + hi4 * 4);
        }

        if (t + 1 < NT) stage(buf ^ 1, t + 1);

        // ---- S^T = K · Q^T (3-term split), k = nf*16 + hi4*4 + i ----
        f32x4 s_acc[4];
        #pragma unroll
        for (int nf = 0; nf < 4; ++nf)
            s_acc[nf] = (f32x4){0.f, 0.f, 0.f, 0.f};

        __builtin_amdgcn_s_setprio(1);
        #pragma unroll
        for (int ks = 0; ks < 2; ++ks)
            #pragma unroll
            for (int nf = 0; nf < 4; ++nf) {
                const int r   = nf * 16 + q16;
                const int off = r * 64 + (((ks * 4 + hi4) ^ (r & 7)) * 8);
                short8 kbh = *(const short8*)(&kvb[buf][0][off]);
                short8 kbl = *(const short8*)(&kvb[buf][1][off]);
                s_acc[nf] = __builtin_amdgcn_mfma_f32_16x16x32_bf16(kbl, qh[ks], s_acc[nf], 0, 0, 0);
                s_acc[nf] = __builtin_amdgcn_mfma_f32_16x16x32_bf16(kbh, ql[ks], s_acc[nf], 0, 0, 0);
                s_acc[nf] = __builtin_amdgcn_mfma_f32_16x16x32_bf16(kbh, qh[ks], s_acc[nf], 0, 0, 0);
            }
        __builtin_amdgcn_s_setprio(0);

        // ---- mask + pos + online softmax (lane-local row q16) ----
        float p[4][4];
        {
            float v[4][4];
            #pragma unroll
            for (int nf = 0; nf < 4; ++nf) {
                const float* km = (const float*)&kmv[nf];
                const float* pr = (const float*)&posr[nf];
                #pragma unroll
                for (int i = 0; i < 4; ++i)
                    v[nf][i] = (qml * km[i] == 0.f)
                               ? -INFINITY : s_acc[nf][i] + pr[i];
            }
            float rm = -INFINITY;
            #pragma unroll
            for (int nf = 0; nf < 4; ++nf)
                #pragma unroll
                for (int i = 0; i < 4; ++i) rm = fmaxf(rm, v[nf][i]);
            rm = fmaxf(rm, __shfl_xor(rm, 16));
            rm = fmaxf(rm, __shfl_xor(rm, 32));
            const float mn = fmaxf(m_run, rm);
            const float c  = __expf(m_run - mn);
            float ls = 0.f;
            #pragma unroll
            for (int nf = 0; nf < 4; ++nf)
                #pragma unroll
                for (int i = 0; i < 4; ++i) {
                    p[nf][i] = __expf(v[nf][i] - mn);
                    ls += p[nf][i];
                }
            ls += __shfl_xor(ls, 16);
            ls += __shfl_xor(ls, 32);
            l_run = l_run * c + ls;
            m_run = mn;
            #pragma unroll
            for (int nfd = 0; nfd < 4; ++nfd)
                o_acc[nfd] *= c;
        }

        // ---- P -> wave-private LDS (16 f32x4 slots/row, slot' = slot ^ q16) ----
        #pragma unroll
        for (int nf = 0; nf < 4; ++nf) {
            const int c4 = (nf * 4 + hi4) ^ q16;
            *(f32x4*)&pp[w][q16 * 64 + c4 * 4] =
                (f32x4){p[nf][0], p[nf][1], p[nf][2], p[nf][3]};
        }

        // ---- P B-frags (trunc split to bf16 hi/lo) ----
        short8 pah[2], pal[2];
        #pragma unroll
        for (int pks = 0; pks < 2; ++pks) {
            const int c4a = (pks * 8 + hi4 * 2)     ^ q16;
            const int c4b = (pks * 8 + hi4 * 2 + 1) ^ q16;
            f32x4 pa = *(const f32x4*)&pp[w][q16 * 64 + c4a * 4];
            f32x4 pb = *(const f32x4*)&pp[w][q16 * 64 + c4b * 4];
            float f[8] = {pa[0], pa[1], pa[2], pa[3], pb[0], pb[1], pb[2], pb[3]};
            short8 hv, lv;
            #pragma unroll
            for (int jj = 0; jj < 8; ++jj) {
                const unsigned u = __builtin_bit_cast(unsigned, f[jj]);
                hv[jj] = (short)(u >> 16);
                const float lof = f[jj] - __builtin_bit_cast(float, u & 0xFFFF0000u);
                lv[jj] = (short)(__builtin_bit_cast(unsigned, lof) >> 16);
            }
            pah[pks] = hv; pal[pks] = lv;
        }

        // ---- PV: O^T = Vt · P^T (3-term split), d = nfd*16 + hi4*4 + i ----
        __builtin_amdgcn_s_setprio(1);
        #pragma unroll
        for (int pks = 0; pks < 2; ++pks)
            #pragma unroll
            for (int nfd = 0; nfd < 4; ++nfd) {
                const int r   = nfd * 16 + q16;
                const int off = r * 64 + (((pks * 4 + hi4) ^ (r & 7)) * 8);
                short8 vbh = *(const short8*)(&kvb[buf][2][off]);
                short8 vbl = *(const short8*)(&kvb[buf][3][off]);
                o_acc[nfd] = __builtin_amdgcn_mfma_f32_16x16x32_bf16(vbl, pah[pks], o_acc[nfd], 0, 0, 0);
                o_acc[nfd] = __builtin_amdgcn_mfma_f32_16x16x32_bf16(vbh, pal[pks], o_acc[nfd], 0, 0, 0);
                o_acc[nfd] = __builtin_amdgcn_mfma_f32_16x16x32_bf16(vbh, pah[pks], o_acc[nfd], 0, 0, 0);
            }
        __builtin_amdgcn_s_setprio(0);

        __syncthreads();   // drain prefetch; all waves done with kvb[buf]
    }

    // ---- normalize + write combined-head (hi,lo) planes [B*L][DMODEL] ----
    {
        const float inv = 1.0f / l_run;
        const size_t rb = (size_t)(b * LL + qw + q16) * DMODEL + h * 64;
        #pragma unroll
        for (int nfd = 0; nfd < 4; ++nfd) {
            ushort4 hv, lv;
            #pragma unroll
            for (int i = 0; i < 4; ++i) {
                const float y  = o_acc[nfd][i] * inv;
                const u16 hh   = f2bf(y);
                (&hv.x)[i] = hh;
                (&lv.x)[i] = f2bf(y - bf2f(hh));
            }
            *(ushort4*)(ach + rb + nfd * 16 + hi4 * 4) = hv;
            *(ushort4*)(acl + rb + nfd * 16 + hi4 * 4) = lv;
        }
    }
}

// ---------------------------------------------------------------------------
extern "C" void kernel_launch(void* const* d_in, const int* in_sizes, int n_in,
                              void* d_out, int out_size, void* d_ws, size_t ws_size,
                              hipStream_t stream)
{
    const float* q     = (const float*)d_in[0];
    const float* k     = (const float*)d_in[1];
    const float* qmask = (const float*)d_in[2];
    const float* kmask = (const float*)d_in[3];
    const float* pos   = (const float*)d_in[4];
    const float* Wq    = (const float*)d_in[5];
    const float* bq    = (const float*)d_in[6];
    const float* Wk    = (const float*)d_in[7];
    const float* bk    = (const float*)d_in[8];
    const float* Wv    = (const float*)d_in[9];
    const float* bv    = (const float*)d_in[10];
    const float* Wo    = (const float*)d_in[11];
    const float* bo    = (const float*)d_in[12];
    float* out = (float*)d_out;

    const size_t P  = (size_t)MTOK * DMODEL;   // 4M elems / plane
    const size_t PW = (size_t)DMODEL * DMODEL;

    u16* base = (u16*)d_ws;
    u16* qp_h = base;            u16* qp_l = qp_h + P;
    u16* kp_h = base + 2 * P;    u16* kp_l = kp_h + P;
    u16* bufA = base + 4 * P;    // q-input planes, later V^T planes (2P)
    u16* bufB = base + 6 * P;    // k-input planes, later attn-out planes (2P)
    u16* wq_h = base + 8 * P;    u16* wq_l = wq_h + PW;
    u16* wk_h = wq_l + PW;       u16* wk_l = wk_h + PW;
    u16* wv_h = wk_l + PW;       u16* wv_l = wv_h + PW;
    u16* wo_h = wv_l + PW;       u16* wo_l = wo_h + PW;
    // total: 8P + 8PW u16 = 80 MB

    // ---- split inputs & weights into bf16 (hi,lo) planes ----
    split_planes2<<<dim3(1024, 2), 256, 0, stream>>>(
        q, bufA, bufA + P, k, bufB, bufB + P, (int)(P / 4));
    split_planes4<<<dim3(512, 4), 256, 0, stream>>>(
        Wq, wq_h, wq_l, Wk, wk_h, wk_l, Wv, wv_h, wv_l, Wo, wo_h, wo_l,
        (int)(PW / 4));

    const dim3 gQK(16, MTOK / 128);            // fused Q+K projection, 512 blocks
    const dim3 g1(8,  MTOK / 128);             // single GEMMs, 256 blocks
    const dim3 ga(LL / 64, NHEAD, BB);         // attention, 1024 blocks

    // Fused: qp = (q @ Wq^T + bq)*0.125 ; kp = k @ Wk^T + bk   -> planes [m][1024]
    gemm_mfma2<<<gQK, 256, 0, stream>>>(
        bufA, bufA + P, wq_h, wq_l, bq, 0.125f, qp_h, qp_l,
        bufB, bufB + P, wk_h, wk_l, bk, 1.0f,   kp_h, kp_l,
        nullptr, DMODEL, DMODEL, 8, 1);
    // vpT = (kp @ Wv^T + bv)^T -> transposed planes [n][MTOK] (into bufA)
    gemm_mfma2<<<g1, 256, 0, stream>>>(
        kp_h, kp_l, wv_h, wv_l, bv, 1.0f, bufA, bufA + P,
        kp_h, kp_l, wv_h, wv_l, bv, 1.0f, bufA, bufA + P,
        nullptr, DMODEL, DMODEL, 8, 2);
    // flash attention v4 -> combined-head planes (into bufB)
    attn_mfma4<<<ga, 256, 0, stream>>>(qp_h, qp_l, kp_h, kp_l, bufA, bufA + P,
                                       qmask, kmask, pos, bufB, bufB + P);
    // out = ac @ Wo^T + bo -> fp32 d_out
    gemm_mfma2<<<g1, 256, 0, stream>>>(
        bufB, bufB + P, wo_h, wo_l, bo, 1.0f, nullptr, nullptr,
        bufB, bufB + P, wo_h, wo_l, bo, 1.0f, nullptr, nullptr,
        out, DMODEL, DMODEL, 8, 0);
}